// Round 7
// baseline (1399.030 us; speedup 1.0000x reference)
//
#include <hip/hip_runtime.h>
#include <hip/hip_bf16.h>
#include <math.h>

#define N_NODES 20000
#define N_EDGES 320000
#define NGRAPH 64

typedef __attribute__((ext_vector_type(8))) short short8;
typedef __attribute__((ext_vector_type(4))) short short4x;
typedef __attribute__((ext_vector_type(4))) float f32x4;

__device__ __forceinline__ float silu_f(float v){ return v / (1.0f + __expf(-v)); }
__device__ __forceinline__ float bf2f(short s){
  unsigned u = ((unsigned)(unsigned short)s) << 16;
  float f; __builtin_memcpy(&f, &u, 4); return f;
}
__device__ __forceinline__ short f2bf(float f){
  unsigned u; __builtin_memcpy(&u, &f, 4);
  unsigned r = (u + 0x7FFFu + ((u >> 16) & 1u)) >> 16;
  return (short)r;
}

// ---------------- CSR build: histogram, scan, scatter ----------------
__global__ void k_hist(const int* __restrict__ ei, int* __restrict__ cnt){
  int e = blockIdx.x*256 + threadIdx.x;
  if (e >= N_EDGES) return;
  atomicAdd(&cnt[ei[N_EDGES + e]], 1);
}

__global__ void k_scan(const int* __restrict__ cnt, int* __restrict__ row_ptr,
                       int* __restrict__ off){
  __shared__ int ssum[256];
  int t = threadIdx.x;
  const int CHK = (N_NODES + 255)/256;
  int base = t*CHK;
  int s = 0;
  for(int i=0;i<CHK;i++){ int idx=base+i; if(idx<N_NODES) s += cnt[idx]; }
  ssum[t]=s; __syncthreads();
  for(int o=1;o<256;o<<=1){
    int v = (t>=o)? ssum[t-o] : 0;
    __syncthreads();
    ssum[t] += v;
    __syncthreads();
  }
  int pre = (t==0)? 0 : ssum[t-1];
  for(int i=0;i<CHK;i++){
    int idx=base+i; if(idx>=N_NODES) break;
    row_ptr[idx]=pre; off[idx]=pre; pre += cnt[idx];
  }
  if(t==255) row_ptr[N_NODES]=pre;
}

__global__ void k_scatter(const int* __restrict__ ei, int* __restrict__ off,
                          int* __restrict__ src_s, int* __restrict__ dst_s,
                          int* __restrict__ eid_s){
  int e = blockIdx.x*256 + threadIdx.x;
  if (e >= N_EDGES) return;
  int d = ei[N_EDGES + e];
  int p = atomicAdd(&off[d], 1);
  dst_s[p]=d; src_s[p]=ei[e]; eid_s[p]=e;
}

// ---------------- edge distance (sorted order) ----------------
__global__ void k_dist_s(const int* __restrict__ src_s, const int* __restrict__ dst_s,
                         const float* __restrict__ pos, float* __restrict__ dist_s){
  int i = blockIdx.x*256 + threadIdx.x;
  if (i >= N_EDGES) return;
  int s = src_s[i], d = dst_s[i];
  float dx = pos[s*3+0]-pos[d*3+0];
  float dy = pos[s*3+1]-pos[d*3+1];
  float dz = pos[s*3+2]-pos[d*3+2];
  dist_s[i] = sqrtf(dx*dx+dy*dy+dz*dz);
}

// ---------------- EA_aug via CSR: per-dst sum of edge_attr, count, zeros (stride 96) ----
__global__ void k_eaagg_s(const int* __restrict__ row_ptr, const int* __restrict__ eid_s,
                          const float* __restrict__ edge_attr, float* __restrict__ EA){
  int sub = threadIdx.x>>6, j = threadIdx.x&63;
  int d = blockIdx.x*4 + sub;
  if (d >= N_NODES) return;
  int b = row_ptr[d], e = row_ptr[d+1];
  float s = 0.f;
  for(int i=b;i<e;i++) s += edge_attr[(size_t)eid_s[i]*64 + j];
  EA[(size_t)d*96 + j] = s;
  if (j < 32) EA[(size_t)d*96 + 64 + j] = (j==0) ? (float)(e-b) : 0.f;
}

// ---------------- fp32 -> bf16 convert ----------------
__global__ void k_f2b(const float* __restrict__ S, short* __restrict__ D, int n4){
  int i = blockIdx.x*256 + threadIdx.x;
  if (i >= n4) return;
  float4 v = ((const float4*)S)[i];
  short4x o;
  o[0]=f2bf(v.x); o[1]=f2bf(v.y); o[2]=f2bf(v.z); o[3]=f2bf(v.w);
  ((short4x*)D)[i] = o;
}

// ---------------- batched weight transposes: z = l*5 + which, fp32[256][256] -> bf16 [n][k] ----
__global__ void k_transW(const float* __restrict__ msg_w1, const float* __restrict__ msg_w2,
                         const float* __restrict__ upd_w1, const float* __restrict__ upd_w2,
                         short* __restrict__ wT){
  int z = blockIdx.z; int l = z/5, w = z%5;
  const float* S;
  switch(w){
    case 0: S = msg_w1 + (size_t)l*513*256; break;
    case 1: S = msg_w1 + (size_t)l*513*256 + 256*256; break;
    case 2: S = msg_w2 + (size_t)l*256*256; break;
    case 3: S = upd_w1 + (size_t)l*256*256; break;
    default: S = upd_w2 + (size_t)l*256*256; break;
  }
  short* D = wT + (size_t)z*65536;
  __shared__ float t[32][33];
  int bx = blockIdx.x*32, by = blockIdx.y*32;
  int lx = threadIdx.x & 31, ly = threadIdx.x >> 5;
  #pragma unroll
  for(int r=0;r<4;r++){ int k = ly + r*8; t[k][lx] = S[(size_t)(by+k)*256 + bx+lx]; }
  __syncthreads();
  #pragma unroll
  for(int r=0;r<4;r++){
    int n = ly + r*8;
    D[(size_t)(bx+n)*256 + by+lx] = f2bf(t[lx][n]);
  }
}

// ---------------- ew_augT [n=256][c=96] bf16, batched over layers (blockIdx.y=l) ----
__global__ void k_ewaugT(const float* __restrict__ edge_w, const float* __restrict__ edge_b,
                         short* __restrict__ ewT4){
  int n = blockIdx.x, c = threadIdx.x, l = blockIdx.y;
  const float* ew = edge_w + (size_t)l*64*256;
  const float* eb = edge_b + l*256;
  float v = (c < 64) ? ew[(size_t)c*256 + n] : (c == 64 ? eb[n] : 0.f);
  ewT4[(size_t)l*24576 + (size_t)n*96 + c] = f2bf(v);
}

// ---------------- biasm accumulation, batched over layers (blockIdx.y=l) ----------------
__global__ void k_biasm_acc(const float* __restrict__ node_b, const float* __restrict__ msg_w1,
                            const float* __restrict__ msg_b1, float* __restrict__ biasm4){
  int j = threadIdx.x;
  int b = blockIdx.x, l = blockIdx.y;
  const float* nb  = node_b + l*256;
  const float* w1  = msg_w1 + (size_t)l*513*256;
  float* biasm = biasm4 + l*256;
  if (b == 16){ atomicAdd(&biasm[j], msg_b1[l*256+j]); return; }
  float s = 0.f;
  for(int k = b*16; k < b*16+16; k++)
    s += nb[k]*(w1[(size_t)k*256+j] + w1[(size_t)(256+k)*256+j]);
  atomicAdd(&biasm[j], s);
}

// ---------------- bf16 MFMA GEMM: C[M,Nld] = A[M,K] @ BT[N,K]^T (+bias)(+silu) ------
// A bf16 (AF32=0) or fp32 (AF32=1, converted during LDS staging).
// blockIdx.z applies element strides AzStr/BzStr/CzStr (batched small GEMMs).
template<int K_REAL, int K_LDS, int AF32, int BIAS, int ACT, int OF32, int OBF16>
__global__ __launch_bounds__(256)
void k_gemm_mfma(const void* __restrict__ A, const short* __restrict__ BT,
                 const float* __restrict__ bias, float* __restrict__ Cf,
                 short* __restrict__ Cb, int M, int Nld,
                 int AzStr, int BzStr, int CzStr){
  __shared__ __align__(16) short As[32][K_LDS];
  const int CHL = K_LDS/8, CH = K_REAL/8;
  int tid = threadIdx.x;
  int zz = blockIdx.z;
  const short* Ab = (const short*)A + (size_t)zz*AzStr;
  const float* Af = (const float*)A + (size_t)zz*AzStr;
  BT += (size_t)zz*BzStr;
  int m0 = blockIdx.y*32, n0 = blockIdx.x*256;
  for(int c = tid; c < 32*CHL; c += 256){
    int row = c / CHL, ch = c % CHL;
    short8 v;
    if (ch < CH) {
      if (AF32){
        float4 f0 = *(const float4*)&Af[(size_t)(m0+row)*K_REAL + ch*8];
        float4 f1 = *(const float4*)&Af[(size_t)(m0+row)*K_REAL + ch*8 + 4];
        v[0]=f2bf(f0.x); v[1]=f2bf(f0.y); v[2]=f2bf(f0.z); v[3]=f2bf(f0.w);
        v[4]=f2bf(f1.x); v[5]=f2bf(f1.y); v[6]=f2bf(f1.z); v[7]=f2bf(f1.w);
      } else {
        v = *(const short8*)&Ab[(size_t)(m0+row)*K_REAL + ch*8];
      }
    } else {
      v = (short8){0,0,0,0,0,0,0,0};
    }
    *(short8*)&As[row][(ch ^ (row&7))*8] = v;
  }
  __syncthreads();
  int wid = tid>>6, lane = tid&63, l15 = lane&15, lq = lane>>4;
  int ncol0 = n0 + wid*64;
  f32x4 acc[2][4];
  #pragma unroll
  for(int mt=0;mt<2;mt++)
    #pragma unroll
    for(int nt=0;nt<4;nt++) acc[mt][nt] = (f32x4){0.f,0.f,0.f,0.f};
  for(int k0=0;k0<K_REAL;k0+=32){
    int kc = k0 + 8*lq;
    short8 a[2], b[4];
    #pragma unroll
    for(int mt=0;mt<2;mt++){
      int row = mt*16 + l15;
      a[mt] = *(const short8*)&As[row][kc ^ ((row&7)<<3)];
    }
    #pragma unroll
    for(int nt=0;nt<4;nt++){
      int col = ncol0 + nt*16 + l15;
      b[nt] = *(const short8*)&BT[(size_t)col*K_REAL + kc];
    }
    #pragma unroll
    for(int mt=0;mt<2;mt++)
      #pragma unroll
      for(int nt=0;nt<4;nt++)
        acc[mt][nt] = __builtin_amdgcn_mfma_f32_16x16x32_bf16(a[mt], b[nt], acc[mt][nt], 0, 0, 0);
  }
  #pragma unroll
  for(int mt=0;mt<2;mt++){
    #pragma unroll
    for(int nt=0;nt<4;nt++){
      int col = ncol0 + nt*16 + l15;
      float bb = BIAS ? bias[col] : 0.f;
      #pragma unroll
      for(int r=0;r<4;r++){
        int row = m0 + mt*16 + lq*4 + r;
        float v = acc[mt][nt][r] + bb;
        if (ACT) v = silu_f(v);
        if (OF32)  Cf[(size_t)zz*CzStr + (size_t)row*Nld + col] = v;
        if (OBF16) Cb[(size_t)zz*CzStr + (size_t)row*Nld + col] = f2bf(v);
      }
    }
  }
}

// ---------------- fused edge kernel (MFMA + two-half segmented reduce) ----------------
// Edges sorted by dst. 32 edges/block. Each thread handles 4 CONSECUTIVE edges and
// caches the t_a[dst] row across them (dst runs, avg degree 16).
// out = silu(h @ w2 + b2) staged half-at-a-time in LDS [col][17]; per-column run scan
// with carried (accu, prev) emits one atomicAdd per distinct dst.
__global__ __launch_bounds__(256)
void k_edge_mfma(const short* __restrict__ t_ab,
                 const float* __restrict__ dist_s,
                 const int* __restrict__ src_s, const int* __restrict__ dst_s,
                 const float* __restrict__ w1c, const float* __restrict__ biasm,
                 const short* __restrict__ w2T, const float* __restrict__ b2,
                 float* __restrict__ aggr)
{
  // union: h [32][256] bf16 (16.0KB) | outl [256][17] f32 (17.0KB)
  __shared__ __align__(16) unsigned char ulds[256*17*4];
  short (*h)[256] = (short(*)[256])ulds;
  float* outl = (float*)ulds;
  __shared__ int sdst[32], ssrc[32];
  __shared__ float sdist[32];
  int tid = threadIdx.x;
  int e0 = blockIdx.x*32;
  if (tid < 32){
    sdst[tid] = dst_s[e0 + tid];
    ssrc[tid] = src_s[e0 + tid];
    sdist[tid] = dist_s[e0 + tid];
  }
  __syncthreads();
  int wid = tid>>6, lane = tid&63;
  int half = lane>>5, cl = lane&31;          // 16B chunk: cols 8cl..8cl+7
  float wc8[8], bm8[8];
  {
    float4 w0 = *(const float4*)&w1c[8*cl], w1v = *(const float4*)&w1c[8*cl+4];
    float4 b0 = *(const float4*)&biasm[8*cl], b1v = *(const float4*)&biasm[8*cl+4];
    wc8[0]=w0.x; wc8[1]=w0.y; wc8[2]=w0.z; wc8[3]=w0.w;
    wc8[4]=w1v.x; wc8[5]=w1v.y; wc8[6]=w1v.z; wc8[7]=w1v.w;
    bm8[0]=b0.x; bm8[1]=b0.y; bm8[2]=b0.z; bm8[3]=b0.w;
    bm8[4]=b1v.x; bm8[5]=b1v.y; bm8[6]=b1v.z; bm8[7]=b1v.w;
  }
  // 4 consecutive edges per thread; reuse t_a[dst] row across equal dsts
  int ebase = wid*8 + half*4;
  int dprev = -1;
  short8 va;
  #pragma unroll
  for(int p=0;p<4;p++){
    int e = ebase + p;
    int d = sdst[e], s = ssrc[e];
    if (d != dprev){
      va = *(const short8*)&t_ab[(size_t)d*512 + 8*cl];
      dprev = d;
    }
    short8 vb = *(const short8*)&t_ab[(size_t)s*512 + 256 + 8*cl];
    float de = sdist[e];
    short8 hv;
    #pragma unroll
    for(int i=0;i<8;i++){
      float f = bf2f(va[i]) + bf2f(vb[i]) + de*wc8[i] + bm8[i];
      hv[i] = f2bf(silu_f(f));
    }
    *(short8*)&h[e][(8*cl) ^ ((e&7)<<3)] = hv;
  }
  __syncthreads();

  int l15 = lane & 15, lq = lane >> 4;
  int nb = wid*64;
  f32x4 acc[2][4];
  #pragma unroll
  for(int mt=0;mt<2;mt++)
    #pragma unroll
    for(int nt=0;nt<4;nt++) acc[mt][nt] = (f32x4){0.f,0.f,0.f,0.f};

  for(int k0=0;k0<256;k0+=32){
    int kc = k0 + 8*lq;
    short8 a[2], b[4];
    #pragma unroll
    for(int mt=0;mt<2;mt++){
      int row = mt*16 + l15;
      a[mt] = *(const short8*)&h[row][kc ^ ((row&7)<<3)];
    }
    #pragma unroll
    for(int nt=0;nt<4;nt++){
      int col = nb + nt*16 + l15;
      b[nt] = *(const short8*)&w2T[(size_t)col*256 + kc];
    }
    #pragma unroll
    for(int mt=0;mt<2;mt++)
      #pragma unroll
      for(int nt=0;nt<4;nt++)
        acc[mt][nt] = __builtin_amdgcn_mfma_f32_16x16x32_bf16(a[mt], b[nt], acc[mt][nt], 0, 0, 0);
  }
  __syncthreads();   // all h reads complete before outl overwrites the union

  // two-half epilogue + segmented scan (column j = tid), carry across halves
  int j = tid;
  float accu = 0.f;
  int prev = sdst[0];
  #pragma unroll
  for(int mt=0;mt<2;mt++){
    #pragma unroll
    for(int nt=0;nt<4;nt++){
      int col = nb + nt*16 + l15;
      float bb = b2[col];
      #pragma unroll
      for(int r=0;r<4;r++){
        int row = lq*4 + r;        // edge-within-half
        outl[col*17 + row] = silu_f(acc[mt][nt][r] + bb);
      }
    }
    __syncthreads();
    #pragma unroll
    for(int e2=0;e2<16;e2++){
      int d = sdst[mt*16 + e2];
      if (d != prev){
        atomicAdd(&aggr[(size_t)prev*256 + j], accu);
        accu = 0.f; prev = d;
      }
      accu += outl[j*17 + e2];
    }
    __syncthreads();
  }
  atomicAdd(&aggr[(size_t)prev*256 + j], accu);
}

// ---------------- batch-segmented pooling ----------------
__global__ void k_ghist(const int* __restrict__ batch, int* __restrict__ gcnt){
  int n = blockIdx.x*256 + threadIdx.x;
  if (n >= N_NODES) return;
  atomicAdd(&gcnt[batch[n]], 1);
}
__global__ void k_gscan(const int* __restrict__ gcnt, int* __restrict__ gptr){
  if (threadIdx.x == 0){
    int s = 0;
    for(int g=0; g<NGRAPH; g++){ gptr[g]=s; s += gcnt[g]; }
    gptr[NGRAPH] = s;
  }
}
__global__ void k_pool_seg(const float* __restrict__ x, const int* __restrict__ gptr,
                           float* __restrict__ pooled){
  int g = blockIdx.x, j = threadIdx.x;
  int b = gptr[g], e = gptr[g+1];
  float s = 0.f;
  for(int n=b; n<e; n++) s += x[(size_t)n*256 + j];
  pooled[g*256 + j] = s;
}

// ---------------- head ----------------
__global__ void k_head(const float* __restrict__ pooled, const float* __restrict__ fw1,
                       const float* __restrict__ fb1, const float* __restrict__ fw2,
                       const float* __restrict__ fb2, float* __restrict__ out){
  __shared__ float red[256];
  int g = blockIdx.x, j = threadIdx.x;
  float s = fb1[j];
  const float* p = &pooled[g*256];
  for(int k=0;k<256;k++) s += p[k]*fw1[k*256+j];
  float hv = silu_f(s)*fw2[j];
  red[j]=hv; __syncthreads();
  for(int off=128;off>0;off>>=1){ if(j<off) red[j]+=red[j+off]; __syncthreads(); }
  if(j==0) out[g] = red[0] + fb2[0];
}

extern "C" void kernel_launch(void* const* d_in, const int* in_sizes, int n_in,
                              void* d_out, int out_size, void* d_ws, size_t ws_size,
                              hipStream_t stream) {
  const float* x_in      = (const float*)d_in[0];
  const float* edge_attr = (const float*)d_in[1];
  const float* pos       = (const float*)d_in[2];
  const int*   ei        = (const int*)d_in[3];
  const int*   batch     = (const int*)d_in[4];
  const float* node_w    = (const float*)d_in[5];
  const float* node_b    = (const float*)d_in[6];
  const float* edge_w    = (const float*)d_in[7];
  const float* edge_b    = (const float*)d_in[8];
  const float* msg_w1    = (const float*)d_in[9];
  const float* msg_b1    = (const float*)d_in[10];
  const float* msg_w2    = (const float*)d_in[11];
  const float* msg_b2    = (const float*)d_in[12];
  const float* upd_w1    = (const float*)d_in[13];
  const float* upd_b1    = (const float*)d_in[14];
  const float* upd_w2    = (const float*)d_in[15];
  const float* upd_b2    = (const float*)d_in[16];
  const float* fc_w1     = (const float*)d_in[17];
  const float* fc_b1     = (const float*)d_in[18];
  const float* fc_w2     = (const float*)d_in[19];
  const float* fc_b2     = (const float*)d_in[20];
  float* out = (float*)d_out;

  float* ws = (float*)d_ws;
  // CSR / sort
  int* cnt     = (int*)ws; ws += N_NODES;
  int* off     = (int*)ws; ws += N_NODES;
  int* row_ptr = (int*)ws; ws += N_NODES+4;
  int* src_s   = (int*)ws; ws += N_EDGES;
  int* dst_s   = (int*)ws; ws += N_EDGES;
  int* eid_s   = (int*)ws; ws += N_EDGES;
  float* dist_s= ws; ws += N_EDGES;
  int* gcnt    = (int*)ws; ws += NGRAPH;
  int* gptr    = (int*)ws; ws += NGRAPH+4;
  // weights (all layers, prepped once)
  short* wT     = (short*)ws; ws += 20*65536/2;      // [l*5+which][256][256] bf16
  short* nw_bf4 = (short*)ws; ws += 4*65536/2;       // node_w bf16, all layers
  short* ewT4   = (short*)ws; ws += 4*24576/2;       // [l][256][96] bf16
  short* WabT4  = (short*)ws; ws += 4*131072/2;      // [l][512][256] bf16
  float* biasm4 = ws; ws += 4*256;
  // data
  short* x_bf   = (short*)ws; ws += (size_t)N_NODES*256/2;
  float* EA_aug = ws; ws += (size_t)N_NODES*96;
  float* tabreg = ws; ws += (size_t)N_NODES*256;     // t_ab bf16 [N][512] / h_bf
  float* aggr   = ws; ws += (size_t)N_NODES*256;
  float* pooled = ws; ws += NGRAPH*256;

  short* t_ab   = (short*)tabreg;
  short* h_bf   = (short*)tabreg;                    // alias: t_ab dead after edge kernel
  float* xfinal = aggr;                              // alias: aggr dead after upd1

  // ---- one-time: CSR sort, distances, EA aggregation, batch ptrs, weight prep ----
  hipMemsetAsync(cnt, 0, N_NODES*sizeof(int), stream);
  k_hist<<<(N_EDGES+255)/256, 256, 0, stream>>>(ei, cnt);
  k_scan<<<1, 256, 0, stream>>>(cnt, row_ptr, off);
  k_scatter<<<(N_EDGES+255)/256, 256, 0, stream>>>(ei, off, src_s, dst_s, eid_s);
  k_dist_s<<<(N_EDGES+255)/256, 256, 0, stream>>>(src_s, dst_s, pos, dist_s);
  k_eaagg_s<<<N_NODES/4, 256, 0, stream>>>(row_ptr, eid_s, edge_attr, EA_aug);
  hipMemsetAsync(gcnt, 0, NGRAPH*sizeof(int), stream);
  k_ghist<<<(N_NODES+255)/256, 256, 0, stream>>>(batch, gcnt);
  k_gscan<<<1, 64, 0, stream>>>(gcnt, gptr);

  k_transW<<<dim3(8,8,20), 256, 0, stream>>>(msg_w1, msg_w2, upd_w1, upd_w2, wT);
  k_ewaugT<<<dim3(256,4), 96, 0, stream>>>(edge_w, edge_b, ewT4);
  k_f2b<<<256, 256, 0, stream>>>(node_w, nw_bf4, 4*65536/4);
  hipMemsetAsync(biasm4, 0, 4*256*sizeof(float), stream);
  k_biasm_acc<<<dim3(17,4), 256, 0, stream>>>(node_b, msg_w1, msg_b1, biasm4);
  // fold node_w through msg_w1 halves, batched over layers (z = l):
  // WabT4 layer block = [512][256] shorts (131072), rows 0-255 = WaT, 256-511 = WbT
  k_gemm_mfma<256,256,0,0,0,0,1><<<dim3(1,8,4), 256, 0, stream>>>(
      wT,          nw_bf4, nullptr, nullptr, WabT4,         256, 256, 5*65536, 65536, 131072);
  k_gemm_mfma<256,256,0,0,0,0,1><<<dim3(1,8,4), 256, 0, stream>>>(
      wT + 65536,  nw_bf4, nullptr, nullptr, WabT4 + 65536, 256, 256, 5*65536, 65536, 131072);

  for(int l=0;l<4;l++){
    const float* w1  = msg_w1 + (size_t)l*513*256;
    const float* mb2 = msg_b2 + l*256;
    const float* ub1 = upd_b1 + l*256;
    const float* ub2 = upd_b2 + l*256;
    const short* w2T_l  = wT + (size_t)(l*5+2)*65536;
    const short* uw1T_l = wT + (size_t)(l*5+3)*65536;
    const short* uw2T_l = wT + (size_t)(l*5+4)*65536;

    // t_ab[N][512] = x @ [Wa|Wb]   (layer 0 reads fp32 x_in directly)
    if (l == 0)
      k_gemm_mfma<256,256,1,0,0,0,1><<<dim3(2,625), 256, 0, stream>>>(
          x_in, WabT4 + (size_t)l*131072, nullptr, nullptr, t_ab, N_NODES, 512, 0,0,0);
    else
      k_gemm_mfma<256,256,0,0,0,0,1><<<dim3(2,625), 256, 0, stream>>>(
          x_bf, WabT4 + (size_t)l*131072, nullptr, nullptr, t_ab, N_NODES, 512, 0,0,0);

    // aggr = EA_aug @ ew_augT (folded edge-embedding segment-sum), fp32 A staged
    k_gemm_mfma<96,128,1,0,0,1,0><<<dim3(1,625), 256, 0, stream>>>(
        EA_aug, ewT4 + (size_t)l*24576, nullptr, aggr, nullptr, N_NODES, 256, 0,0,0);

    k_edge_mfma<<<N_EDGES/32, 256, 0, stream>>>(t_ab, dist_s, src_s, dst_s,
                                                w1 + 512*256, biasm4 + l*256,
                                                w2T_l, mb2, aggr);

    // update MLP (upd1 reads fp32 aggr directly)
    k_gemm_mfma<256,256,1,1,1,0,1><<<dim3(1,625), 256, 0, stream>>>(
        aggr, uw1T_l, ub1, nullptr, h_bf, N_NODES, 256, 0,0,0);
    if (l < 3)
      k_gemm_mfma<256,256,0,1,0,0,1><<<dim3(1,625), 256, 0, stream>>>(
          h_bf, uw2T_l, ub2, nullptr, x_bf, N_NODES, 256, 0,0,0);
    else
      k_gemm_mfma<256,256,0,1,0,1,0><<<dim3(1,625), 256, 0, stream>>>(
          h_bf, uw2T_l, ub2, xfinal, nullptr, N_NODES, 256, 0,0,0);
  }

  k_pool_seg<<<NGRAPH, 256, 0, stream>>>(xfinal, gptr, pooled);
  k_head<<<NGRAPH, 256, 0, stream>>>(pooled, fc_w1, fc_b1, fc_w2, fc_b2, out);
}

// Round 8
// 1323.401 us; speedup vs baseline: 1.0571x; 1.0571x over previous
//
#include <hip/hip_runtime.h>
#include <hip/hip_bf16.h>
#include <math.h>

#define N_NODES 20000
#define N_EDGES 320000
#define NGRAPH 64

typedef __attribute__((ext_vector_type(8))) short short8;
typedef __attribute__((ext_vector_type(4))) short short4x;
typedef __attribute__((ext_vector_type(4))) float f32x4;

__device__ __forceinline__ float silu_f(float v){ return v / (1.0f + __expf(-v)); }
__device__ __forceinline__ float bf2f(short s){
  unsigned u = ((unsigned)(unsigned short)s) << 16;
  float f; __builtin_memcpy(&f, &u, 4); return f;
}
__device__ __forceinline__ short f2bf(float f){
  unsigned u; __builtin_memcpy(&u, &f, 4);
  unsigned r = (u + 0x7FFFu + ((u >> 16) & 1u)) >> 16;
  return (short)r;
}

// ---------------- CSR build: histogram, scan, scatter ----------------
__global__ void k_hist(const int* __restrict__ ei, int* __restrict__ cnt){
  int e = blockIdx.x*256 + threadIdx.x;
  if (e >= N_EDGES) return;
  atomicAdd(&cnt[ei[N_EDGES + e]], 1);
}

__global__ void k_scan(const int* __restrict__ cnt, int* __restrict__ row_ptr,
                       int* __restrict__ off){
  __shared__ int ssum[256];
  int t = threadIdx.x;
  const int CHK = (N_NODES + 255)/256;
  int base = t*CHK;
  int s = 0;
  for(int i=0;i<CHK;i++){ int idx=base+i; if(idx<N_NODES) s += cnt[idx]; }
  ssum[t]=s; __syncthreads();
  for(int o=1;o<256;o<<=1){
    int v = (t>=o)? ssum[t-o] : 0;
    __syncthreads();
    ssum[t] += v;
    __syncthreads();
  }
  int pre = (t==0)? 0 : ssum[t-1];
  for(int i=0;i<CHK;i++){
    int idx=base+i; if(idx>=N_NODES) break;
    row_ptr[idx]=pre; off[idx]=pre; pre += cnt[idx];
  }
  if(t==255) row_ptr[N_NODES]=pre;
}

__global__ void k_scatter(const int* __restrict__ ei, int* __restrict__ off,
                          int* __restrict__ src_s, int* __restrict__ dst_s,
                          int* __restrict__ eid_s){
  int e = blockIdx.x*256 + threadIdx.x;
  if (e >= N_EDGES) return;
  int d = ei[N_EDGES + e];
  int p = atomicAdd(&off[d], 1);
  dst_s[p]=d; src_s[p]=ei[e]; eid_s[p]=e;
}

// ---------------- edge distance (sorted order) ----------------
__global__ void k_dist_s(const int* __restrict__ src_s, const int* __restrict__ dst_s,
                         const float* __restrict__ pos, float* __restrict__ dist_s){
  int i = blockIdx.x*256 + threadIdx.x;
  if (i >= N_EDGES) return;
  int s = src_s[i], d = dst_s[i];
  float dx = pos[s*3+0]-pos[d*3+0];
  float dy = pos[s*3+1]-pos[d*3+1];
  float dz = pos[s*3+2]-pos[d*3+2];
  dist_s[i] = sqrtf(dx*dx+dy*dy+dz*dz);
}

// ---------------- EA_aug via CSR: per-dst sum of edge_attr, count, zeros (stride 96) ----
__global__ void k_eaagg_s(const int* __restrict__ row_ptr, const int* __restrict__ eid_s,
                          const float* __restrict__ edge_attr, float* __restrict__ EA){
  int sub = threadIdx.x>>6, j = threadIdx.x&63;
  int d = blockIdx.x*4 + sub;
  if (d >= N_NODES) return;
  int b = row_ptr[d], e = row_ptr[d+1];
  float s = 0.f;
  for(int i=b;i<e;i++) s += edge_attr[(size_t)eid_s[i]*64 + j];
  EA[(size_t)d*96 + j] = s;
  if (j < 32) EA[(size_t)d*96 + 64 + j] = (j==0) ? (float)(e-b) : 0.f;
}

// ---------------- fp32 -> bf16 convert ----------------
__global__ void k_f2b(const float* __restrict__ S, short* __restrict__ D, int n4){
  int i = blockIdx.x*256 + threadIdx.x;
  if (i >= n4) return;
  float4 v = ((const float4*)S)[i];
  short4x o;
  o[0]=f2bf(v.x); o[1]=f2bf(v.y); o[2]=f2bf(v.z); o[3]=f2bf(v.w);
  ((short4x*)D)[i] = o;
}

// ---------------- batched weight transposes: z = l*5 + which, fp32[256][256] -> bf16 [n][k] ----
__global__ void k_transW(const float* __restrict__ msg_w1, const float* __restrict__ msg_w2,
                         const float* __restrict__ upd_w1, const float* __restrict__ upd_w2,
                         short* __restrict__ wT){
  int z = blockIdx.z; int l = z/5, w = z%5;
  const float* S;
  switch(w){
    case 0: S = msg_w1 + (size_t)l*513*256; break;
    case 1: S = msg_w1 + (size_t)l*513*256 + 256*256; break;
    case 2: S = msg_w2 + (size_t)l*256*256; break;
    case 3: S = upd_w1 + (size_t)l*256*256; break;
    default: S = upd_w2 + (size_t)l*256*256; break;
  }
  short* D = wT + (size_t)z*65536;
  __shared__ float t[32][33];
  int bx = blockIdx.x*32, by = blockIdx.y*32;
  int lx = threadIdx.x & 31, ly = threadIdx.x >> 5;
  #pragma unroll
  for(int r=0;r<4;r++){ int k = ly + r*8; t[k][lx] = S[(size_t)(by+k)*256 + bx+lx]; }
  __syncthreads();
  #pragma unroll
  for(int r=0;r<4;r++){
    int n = ly + r*8;
    D[(size_t)(bx+n)*256 + by+lx] = f2bf(t[lx][n]);
  }
}

// ---------------- ew_augT [n=256][c=96] bf16, batched over layers (blockIdx.y=l) ----
__global__ void k_ewaugT(const float* __restrict__ edge_w, const float* __restrict__ edge_b,
                         short* __restrict__ ewT4){
  int n = blockIdx.x, c = threadIdx.x, l = blockIdx.y;
  const float* ew = edge_w + (size_t)l*64*256;
  const float* eb = edge_b + l*256;
  float v = (c < 64) ? ew[(size_t)c*256 + n] : (c == 64 ? eb[n] : 0.f);
  ewT4[(size_t)l*24576 + (size_t)n*96 + c] = f2bf(v);
}

// ---------------- biasm accumulation, batched over layers (blockIdx.y=l) ----------------
__global__ void k_biasm_acc(const float* __restrict__ node_b, const float* __restrict__ msg_w1,
                            const float* __restrict__ msg_b1, float* __restrict__ biasm4){
  int j = threadIdx.x;
  int b = blockIdx.x, l = blockIdx.y;
  const float* nb  = node_b + l*256;
  const float* w1  = msg_w1 + (size_t)l*513*256;
  float* biasm = biasm4 + l*256;
  if (b == 16){ atomicAdd(&biasm[j], msg_b1[l*256+j]); return; }
  float s = 0.f;
  for(int k = b*16; k < b*16+16; k++)
    s += nb[k]*(w1[(size_t)k*256+j] + w1[(size_t)(256+k)*256+j]);
  atomicAdd(&biasm[j], s);
}

// ---------------- biasm += ub2_{l-1} @ (Wa_l + Wb_l), l = blockIdx.x+1 ----------------
__global__ void k_biasfold(const float* __restrict__ upd_b2, const short* __restrict__ WabT4,
                           float* __restrict__ biasm4){
  int l = blockIdx.x + 1;           // 1..3
  int j = threadIdx.x;
  const float* ub2 = upd_b2 + (size_t)(l-1)*256;
  const short* W = WabT4 + (size_t)l*131072;
  float s = 0.f;
  for(int k=0;k<256;k++)
    s += ub2[k]*(bf2f(W[(size_t)j*256+k]) + bf2f(W[(size_t)(256+j)*256+k]));
  biasm4[l*256 + j] += s;
}

// ---------------- bf16 MFMA GEMM: C[M,Nld] = A[M,K] @ BT[N,K]^T (+bias)(+silu) ------
// A bf16 (AF32=0) or fp32 (AF32=1, converted during LDS staging).
// blockIdx.z applies element strides AzStr/BzStr/CzStr (batched small GEMMs).
template<int K_REAL, int K_LDS, int AF32, int BIAS, int ACT, int OF32, int OBF16>
__global__ __launch_bounds__(256)
void k_gemm_mfma(const void* __restrict__ A, const short* __restrict__ BT,
                 const float* __restrict__ bias, float* __restrict__ Cf,
                 short* __restrict__ Cb, int M, int Nld,
                 int AzStr, int BzStr, int CzStr){
  __shared__ __align__(16) short As[32][K_LDS];
  const int CHL = K_LDS/8, CH = K_REAL/8;
  int tid = threadIdx.x;
  int zz = blockIdx.z;
  const short* Ab = (const short*)A + (size_t)zz*AzStr;
  const float* Af = (const float*)A + (size_t)zz*AzStr;
  BT += (size_t)zz*BzStr;
  int m0 = blockIdx.y*32, n0 = blockIdx.x*256;
  for(int c = tid; c < 32*CHL; c += 256){
    int row = c / CHL, ch = c % CHL;
    short8 v;
    if (ch < CH) {
      if (AF32){
        float4 f0 = *(const float4*)&Af[(size_t)(m0+row)*K_REAL + ch*8];
        float4 f1 = *(const float4*)&Af[(size_t)(m0+row)*K_REAL + ch*8 + 4];
        v[0]=f2bf(f0.x); v[1]=f2bf(f0.y); v[2]=f2bf(f0.z); v[3]=f2bf(f0.w);
        v[4]=f2bf(f1.x); v[5]=f2bf(f1.y); v[6]=f2bf(f1.z); v[7]=f2bf(f1.w);
      } else {
        v = *(const short8*)&Ab[(size_t)(m0+row)*K_REAL + ch*8];
      }
    } else {
      v = (short8){0,0,0,0,0,0,0,0};
    }
    *(short8*)&As[row][(ch ^ (row&7))*8] = v;
  }
  __syncthreads();
  int wid = tid>>6, lane = tid&63, l15 = lane&15, lq = lane>>4;
  int ncol0 = n0 + wid*64;
  f32x4 acc[2][4];
  #pragma unroll
  for(int mt=0;mt<2;mt++)
    #pragma unroll
    for(int nt=0;nt<4;nt++) acc[mt][nt] = (f32x4){0.f,0.f,0.f,0.f};
  for(int k0=0;k0<K_REAL;k0+=32){
    int kc = k0 + 8*lq;
    short8 a[2], b[4];
    #pragma unroll
    for(int mt=0;mt<2;mt++){
      int row = mt*16 + l15;
      a[mt] = *(const short8*)&As[row][kc ^ ((row&7)<<3)];
    }
    #pragma unroll
    for(int nt=0;nt<4;nt++){
      int col = ncol0 + nt*16 + l15;
      b[nt] = *(const short8*)&BT[(size_t)col*K_REAL + kc];
    }
    #pragma unroll
    for(int mt=0;mt<2;mt++)
      #pragma unroll
      for(int nt=0;nt<4;nt++)
        acc[mt][nt] = __builtin_amdgcn_mfma_f32_16x16x32_bf16(a[mt], b[nt], acc[mt][nt], 0, 0, 0);
  }
  #pragma unroll
  for(int mt=0;mt<2;mt++){
    #pragma unroll
    for(int nt=0;nt<4;nt++){
      int col = ncol0 + nt*16 + l15;
      float bb = BIAS ? bias[col] : 0.f;
      #pragma unroll
      for(int r=0;r<4;r++){
        int row = m0 + mt*16 + lq*4 + r;
        float v = acc[mt][nt][r] + bb;
        if (ACT) v = silu_f(v);
        if (OF32)  Cf[(size_t)zz*CzStr + (size_t)row*Nld + col] = v;
        if (OBF16) Cb[(size_t)zz*CzStr + (size_t)row*Nld + col] = f2bf(v);
      }
    }
  }
}

// ---------------- fused edge kernel: 64 edges/block, B-frag reuse across 2 sub-tiles ----
// Edges sorted by dst. gather (strided, unconditional) -> h[64][256] bf16 swizzled ->
// MFMA h@w2 with b-frags loaded ONCE per k-step for both 32-edge subs ->
// two-pass epilogue + segmented scan, one atomicAdd per distinct dst per column.
__global__ __launch_bounds__(256)
void k_edge_mfma(const short* __restrict__ t_ab,
                 const float* __restrict__ dist_s,
                 const int* __restrict__ src_s, const int* __restrict__ dst_s,
                 const float* __restrict__ w1c, const float* __restrict__ biasm,
                 const short* __restrict__ w2T, const float* __restrict__ b2,
                 float* __restrict__ aggr)
{
  // union: h [64][256] bf16 (32KB) | outl [256][33] f32 (33.8KB)
  __shared__ __align__(16) unsigned char ulds[256*33*4];
  short (*h)[256] = (short(*)[256])ulds;
  float* outl = (float*)ulds;
  __shared__ int sdst[64], ssrc[64];
  __shared__ float sdist[64];
  int tid = threadIdx.x;
  int e0 = blockIdx.x*64;
  if (tid < 64){
    sdst[tid] = dst_s[e0 + tid];
    ssrc[tid] = src_s[e0 + tid];
    sdist[tid] = dist_s[e0 + tid];
  }
  __syncthreads();
  int cl = tid & 31, slot = tid >> 5;        // 16B chunk cl, edge-slot 0..7
  float wc8[8], bm8[8];
  {
    float4 w0 = *(const float4*)&w1c[8*cl], w1v = *(const float4*)&w1c[8*cl+4];
    float4 b0 = *(const float4*)&biasm[8*cl], b1v = *(const float4*)&biasm[8*cl+4];
    wc8[0]=w0.x; wc8[1]=w0.y; wc8[2]=w0.z; wc8[3]=w0.w;
    wc8[4]=w1v.x; wc8[5]=w1v.y; wc8[6]=w1v.z; wc8[7]=w1v.w;
    bm8[0]=b0.x; bm8[1]=b0.y; bm8[2]=b0.z; bm8[3]=b0.w;
    bm8[4]=b1v.x; bm8[5]=b1v.y; bm8[6]=b1v.z; bm8[7]=b1v.w;
  }
  // 8 strided edges per thread, unconditional loads (max MLP)
  #pragma unroll
  for(int p=0;p<8;p++){
    int e = slot + p*8;
    int d = sdst[e], s = ssrc[e];
    float de = sdist[e];
    short8 va = *(const short8*)&t_ab[(size_t)d*512 + 8*cl];
    short8 vb = *(const short8*)&t_ab[(size_t)s*512 + 256 + 8*cl];
    short8 hv;
    #pragma unroll
    for(int i=0;i<8;i++){
      float f = bf2f(va[i]) + bf2f(vb[i]) + de*wc8[i] + bm8[i];
      hv[i] = f2bf(silu_f(f));
    }
    *(short8*)&h[e][(8*cl) ^ ((e&7)<<3)] = hv;
  }
  __syncthreads();

  int wid = tid>>6, lane = tid&63, l15 = lane&15, lq = lane>>4;
  int nb = wid*64;
  f32x4 acc[2][2][4];
  #pragma unroll
  for(int s=0;s<2;s++)
    #pragma unroll
    for(int mt=0;mt<2;mt++)
      #pragma unroll
      for(int nt=0;nt<4;nt++) acc[s][mt][nt] = (f32x4){0.f,0.f,0.f,0.f};

  for(int k0=0;k0<256;k0+=32){
    int kc = k0 + 8*lq;
    short8 b[4];
    #pragma unroll
    for(int nt=0;nt<4;nt++){
      int col = nb + nt*16 + l15;
      b[nt] = *(const short8*)&w2T[(size_t)col*256 + kc];
    }
    short8 a[2][2];
    #pragma unroll
    for(int s=0;s<2;s++)
      #pragma unroll
      for(int mt=0;mt<2;mt++){
        int row = s*32 + mt*16 + l15;
        a[s][mt] = *(const short8*)&h[row][kc ^ ((row&7)<<3)];
      }
    #pragma unroll
    for(int s=0;s<2;s++)
      #pragma unroll
      for(int mt=0;mt<2;mt++)
        #pragma unroll
        for(int nt=0;nt<4;nt++)
          acc[s][mt][nt] = __builtin_amdgcn_mfma_f32_16x16x32_bf16(a[s][mt], b[nt], acc[s][mt][nt], 0, 0, 0);
  }
  __syncthreads();   // all h reads complete before outl overwrites the union

  // two-pass epilogue + segmented scan (column j = tid), carry across passes
  int j = tid;
  float accu = 0.f;
  int prev = sdst[0];
  #pragma unroll
  for(int s=0;s<2;s++){
    #pragma unroll
    for(int mt=0;mt<2;mt++){
      #pragma unroll
      for(int nt=0;nt<4;nt++){
        int col = nb + nt*16 + l15;
        float bb = b2[col];
        #pragma unroll
        for(int r=0;r<4;r++){
          int row = mt*16 + lq*4 + r;        // edge within sub
          outl[col*33 + row] = silu_f(acc[s][mt][nt][r] + bb);
        }
      }
    }
    __syncthreads();
    #pragma unroll
    for(int e2=0;e2<32;e2++){
      int d = sdst[s*32 + e2];
      if (d != prev){
        atomicAdd(&aggr[(size_t)prev*256 + j], accu);
        accu = 0.f; prev = d;
      }
      accu += outl[j*33 + e2];
    }
    __syncthreads();
  }
  atomicAdd(&aggr[(size_t)prev*256 + j], accu);
}

// ---------------- batch-segmented pooling ----------------
__global__ void k_ghist(const int* __restrict__ batch, int* __restrict__ gcnt){
  int n = blockIdx.x*256 + threadIdx.x;
  if (n >= N_NODES) return;
  atomicAdd(&gcnt[batch[n]], 1);
}
__global__ void k_gscan(const int* __restrict__ gcnt, int* __restrict__ gptr){
  if (threadIdx.x == 0){
    int s = 0;
    for(int g=0; g<NGRAPH; g++){ gptr[g]=s; s += gcnt[g]; }
    gptr[NGRAPH] = s;
  }
}
__global__ void k_pool_seg(const float* __restrict__ x, const int* __restrict__ gptr,
                           float* __restrict__ pooled){
  int g = blockIdx.x, j = threadIdx.x;
  int b = gptr[g], e = gptr[g+1];
  float s = 0.f;
  for(int n=b; n<e; n++) s += x[(size_t)n*256 + j];
  pooled[g*256 + j] = s;
}

// ---------------- head ----------------
__global__ void k_head(const float* __restrict__ pooled, const float* __restrict__ fw1,
                       const float* __restrict__ fb1, const float* __restrict__ fw2,
                       const float* __restrict__ fb2, float* __restrict__ out){
  __shared__ float red[256];
  int g = blockIdx.x, j = threadIdx.x;
  float s = fb1[j];
  const float* p = &pooled[g*256];
  for(int k=0;k<256;k++) s += p[k]*fw1[k*256+j];
  float hv = silu_f(s)*fw2[j];
  red[j]=hv; __syncthreads();
  for(int off=128;off>0;off>>=1){ if(j<off) red[j]+=red[j+off]; __syncthreads(); }
  if(j==0) out[g] = red[0] + fb2[0];
}

extern "C" void kernel_launch(void* const* d_in, const int* in_sizes, int n_in,
                              void* d_out, int out_size, void* d_ws, size_t ws_size,
                              hipStream_t stream) {
  const float* x_in      = (const float*)d_in[0];
  const float* edge_attr = (const float*)d_in[1];
  const float* pos       = (const float*)d_in[2];
  const int*   ei        = (const int*)d_in[3];
  const int*   batch     = (const int*)d_in[4];
  const float* node_w    = (const float*)d_in[5];
  const float* node_b    = (const float*)d_in[6];
  const float* edge_w    = (const float*)d_in[7];
  const float* edge_b    = (const float*)d_in[8];
  const float* msg_w1    = (const float*)d_in[9];
  const float* msg_b1    = (const float*)d_in[10];
  const float* msg_w2    = (const float*)d_in[11];
  const float* msg_b2    = (const float*)d_in[12];
  const float* upd_w1    = (const float*)d_in[13];
  const float* upd_b1    = (const float*)d_in[14];
  const float* upd_w2    = (const float*)d_in[15];
  const float* upd_b2    = (const float*)d_in[16];
  const float* fc_w1     = (const float*)d_in[17];
  const float* fc_b1     = (const float*)d_in[18];
  const float* fc_w2     = (const float*)d_in[19];
  const float* fc_b2     = (const float*)d_in[20];
  float* out = (float*)d_out;

  float* ws = (float*)d_ws;
  // CSR / sort
  int* cnt     = (int*)ws; ws += N_NODES;
  int* off     = (int*)ws; ws += N_NODES;
  int* row_ptr = (int*)ws; ws += N_NODES+4;
  int* src_s   = (int*)ws; ws += N_EDGES;
  int* dst_s   = (int*)ws; ws += N_EDGES;
  int* eid_s   = (int*)ws; ws += N_EDGES;
  float* dist_s= ws; ws += N_EDGES;
  int* gcnt    = (int*)ws; ws += NGRAPH;
  int* gptr    = (int*)ws; ws += NGRAPH+4;
  // weights (all layers, prepped once)
  short* wT      = (short*)ws; ws += 20*65536/2;     // [l*5+which][256][256] bf16
  short* nw_bf4  = (short*)ws; ws += 4*65536/2;      // node_w bf16
  short* uw2_bf4 = (short*)ws; ws += 4*65536/2;      // upd_w2 bf16 (row-major, for fold)
  short* ewT4    = (short*)ws; ws += 4*24576/2;      // [l][256][96] bf16
  short* WabT4   = (short*)ws; ws += 4*131072/2;     // [l][512][256] bf16
  short* WfoldT4 = (short*)ws; ws += 3*131072/2;     // [l=1..3][512][256] bf16
  float* biasm4  = ws; ws += 4*256;
  // data
  short* h_bf   = (short*)ws; ws += (size_t)N_NODES*256/2;   // silu(aggr@uw1+ub1) bf16
  float* EA_aug = ws; ws += (size_t)N_NODES*96;
  float* tabreg = ws; ws += (size_t)N_NODES*256;             // t_ab bf16 [N][512]
  float* aggr   = ws; ws += (size_t)N_NODES*256;
  float* pooled = ws; ws += NGRAPH*256;

  short* t_ab   = (short*)tabreg;
  float* xfinal = aggr;                              // alias: aggr dead after upd1

  // ---- one-time: CSR sort, distances, EA aggregation, batch ptrs, weight prep ----
  hipMemsetAsync(cnt, 0, N_NODES*sizeof(int), stream);
  k_hist<<<(N_EDGES+255)/256, 256, 0, stream>>>(ei, cnt);
  k_scan<<<1, 256, 0, stream>>>(cnt, row_ptr, off);
  k_scatter<<<(N_EDGES+255)/256, 256, 0, stream>>>(ei, off, src_s, dst_s, eid_s);
  k_dist_s<<<(N_EDGES+255)/256, 256, 0, stream>>>(src_s, dst_s, pos, dist_s);
  k_eaagg_s<<<N_NODES/4, 256, 0, stream>>>(row_ptr, eid_s, edge_attr, EA_aug);
  hipMemsetAsync(gcnt, 0, NGRAPH*sizeof(int), stream);
  k_ghist<<<(N_NODES+255)/256, 256, 0, stream>>>(batch, gcnt);
  k_gscan<<<1, 64, 0, stream>>>(gcnt, gptr);

  k_transW<<<dim3(8,8,20), 256, 0, stream>>>(msg_w1, msg_w2, upd_w1, upd_w2, wT);
  k_ewaugT<<<dim3(256,4), 96, 0, stream>>>(edge_w, edge_b, ewT4);
  k_f2b<<<256, 256, 0, stream>>>(node_w, nw_bf4, 4*65536/4);
  k_f2b<<<256, 256, 0, stream>>>(upd_w2, uw2_bf4, 4*65536/4);
  hipMemsetAsync(biasm4, 0, 4*256*sizeof(float), stream);
  k_biasm_acc<<<dim3(17,4), 256, 0, stream>>>(node_b, msg_w1, msg_b1, biasm4);
  // fold node_w through msg_w1 halves, batched over layers (z = l):
  // WabT4 layer block = [512][256] shorts, rows 0-255 = WaT, 256-511 = WbT
  k_gemm_mfma<256,256,0,0,0,0,1><<<dim3(1,8,4), 256, 0, stream>>>(
      wT,          nw_bf4, nullptr, nullptr, WabT4,         256, 256, 5*65536, 65536, 131072);
  k_gemm_mfma<256,256,0,0,0,0,1><<<dim3(1,8,4), 256, 0, stream>>>(
      wT + 65536,  nw_bf4, nullptr, nullptr, WabT4 + 65536, 256, 256, 5*65536, 65536, 131072);
  // fold upd_w2 into next layer's Wab: WfoldT[l] = WabT4[l] @ uw2_{l-1}, l=1..3 (z=0..2)
  k_gemm_mfma<256,256,0,0,0,0,1><<<dim3(1,16,3), 256, 0, stream>>>(
      WabT4 + 131072, uw2_bf4, nullptr, nullptr, WfoldT4, 512, 256, 131072, 65536, 131072);
  // biasm_l += ub2_{l-1} @ (Wa_l + Wb_l), l=1..3
  k_biasfold<<<3, 256, 0, stream>>>(upd_b2, WabT4, biasm4);

  // t_ab for layer 0: x_in @ [Wa0|Wb0] (fp32 A staged)
  k_gemm_mfma<256,256,1,0,0,0,1><<<dim3(2,625), 256, 0, stream>>>(
      x_in, WabT4, nullptr, nullptr, t_ab, N_NODES, 512, 0,0,0);

  for(int l=0;l<4;l++){
    const float* w1  = msg_w1 + (size_t)l*513*256;
    const float* mb2 = msg_b2 + l*256;
    const float* ub1 = upd_b1 + l*256;
    const float* ub2 = upd_b2 + l*256;
    const short* w2T_l  = wT + (size_t)(l*5+2)*65536;
    const short* uw1T_l = wT + (size_t)(l*5+3)*65536;
    const short* uw2T_l = wT + (size_t)(l*5+4)*65536;

    // aggr = EA_aug @ ew_augT (folded edge-embedding segment-sum), fp32 A staged
    k_gemm_mfma<96,128,1,0,0,1,0><<<dim3(1,625), 256, 0, stream>>>(
        EA_aug, ewT4 + (size_t)l*24576, nullptr, aggr, nullptr, N_NODES, 256, 0,0,0);

    k_edge_mfma<<<N_EDGES/64, 256, 0, stream>>>(t_ab, dist_s, src_s, dst_s,
                                                w1 + 512*256, biasm4 + l*256,
                                                w2T_l, mb2, aggr);

    // h_bf = silu(aggr @ uw1 + ub1)  (fp32 A staged, bf16 out)
    k_gemm_mfma<256,256,1,1,1,0,1><<<dim3(1,625), 256, 0, stream>>>(
        aggr, uw1T_l, ub1, nullptr, h_bf, N_NODES, 256, 0,0,0);

    if (l < 3)
      // next-layer t_ab directly: h_bf @ WfoldT[l+1]  (upd2 folded; bias in biasm4[l+1])
      k_gemm_mfma<256,256,0,0,0,0,1><<<dim3(2,625), 256, 0, stream>>>(
          h_bf, WfoldT4 + (size_t)l*131072, nullptr, nullptr, t_ab, N_NODES, 512, 0,0,0);
    else
      // final x for pooling: h_bf @ uw2 + ub2
      k_gemm_mfma<256,256,0,1,0,1,0><<<dim3(1,625), 256, 0, stream>>>(
          h_bf, uw2T_l, ub2, xfinal, nullptr, N_NODES, 256, 0,0,0);
  }

  k_pool_seg<<<NGRAPH, 256, 0, stream>>>(xfinal, gptr, pooled);
  k_head<<<NGRAPH, 256, 0, stream>>>(pooled, fc_w1, fc_b1, fc_w2, fc_b2, out);
}

// Round 9
// 1298.289 us; speedup vs baseline: 1.0776x; 1.0193x over previous
//
#include <hip/hip_runtime.h>
#include <hip/hip_bf16.h>
#include <math.h>

#define N_NODES 20000
#define N_EDGES 320000
#define NGRAPH 64

typedef __attribute__((ext_vector_type(8))) short short8;
typedef __attribute__((ext_vector_type(4))) short short4x;
typedef __attribute__((ext_vector_type(4))) float f32x4;

__device__ __forceinline__ float silu_f(float v){ return v / (1.0f + __expf(-v)); }
__device__ __forceinline__ float bf2f(short s){
  unsigned u = ((unsigned)(unsigned short)s) << 16;
  float f; __builtin_memcpy(&f, &u, 4); return f;
}
__device__ __forceinline__ short f2bf(float f){
  unsigned u; __builtin_memcpy(&u, &f, 4);
  unsigned r = (u + 0x7FFFu + ((u >> 16) & 1u)) >> 16;
  return (short)r;
}

// ---------------- CSR build: histogram, scan, scatter ----------------
__global__ void k_hist(const int* __restrict__ ei, int* __restrict__ cnt){
  int e = blockIdx.x*256 + threadIdx.x;
  if (e >= N_EDGES) return;
  atomicAdd(&cnt[ei[N_EDGES + e]], 1);
}

__global__ void k_scan(const int* __restrict__ cnt, int* __restrict__ row_ptr,
                       int* __restrict__ off){
  __shared__ int ssum[256];
  int t = threadIdx.x;
  const int CHK = (N_NODES + 255)/256;
  int base = t*CHK;
  int s = 0;
  for(int i=0;i<CHK;i++){ int idx=base+i; if(idx<N_NODES) s += cnt[idx]; }
  ssum[t]=s; __syncthreads();
  for(int o=1;o<256;o<<=1){
    int v = (t>=o)? ssum[t-o] : 0;
    __syncthreads();
    ssum[t] += v;
    __syncthreads();
  }
  int pre = (t==0)? 0 : ssum[t-1];
  for(int i=0;i<CHK;i++){
    int idx=base+i; if(idx>=N_NODES) break;
    row_ptr[idx]=pre; off[idx]=pre; pre += cnt[idx];
  }
  if(t==255) row_ptr[N_NODES]=pre;
}

__global__ void k_scatter(const int* __restrict__ ei, int* __restrict__ off,
                          int* __restrict__ src_s, int* __restrict__ dst_s,
                          int* __restrict__ eid_s){
  int e = blockIdx.x*256 + threadIdx.x;
  if (e >= N_EDGES) return;
  int d = ei[N_EDGES + e];
  int p = atomicAdd(&off[d], 1);
  dst_s[p]=d; src_s[p]=ei[e]; eid_s[p]=e;
}

// ---------------- edge distance (sorted order) ----------------
__global__ void k_dist_s(const int* __restrict__ src_s, const int* __restrict__ dst_s,
                         const float* __restrict__ pos, float* __restrict__ dist_s){
  int i = blockIdx.x*256 + threadIdx.x;
  if (i >= N_EDGES) return;
  int s = src_s[i], d = dst_s[i];
  float dx = pos[s*3+0]-pos[d*3+0];
  float dy = pos[s*3+1]-pos[d*3+1];
  float dz = pos[s*3+2]-pos[d*3+2];
  dist_s[i] = sqrtf(dx*dx+dy*dy+dz*dz);
}

// ---------------- EA_aug via CSR: per-dst sum of edge_attr, count, zeros (stride 96) ----
__global__ void k_eaagg_s(const int* __restrict__ row_ptr, const int* __restrict__ eid_s,
                          const float* __restrict__ edge_attr, float* __restrict__ EA){
  int sub = threadIdx.x>>6, j = threadIdx.x&63;
  int d = blockIdx.x*4 + sub;
  if (d >= N_NODES) return;
  int b = row_ptr[d], e = row_ptr[d+1];
  float s = 0.f;
  for(int i=b;i<e;i++) s += edge_attr[(size_t)eid_s[i]*64 + j];
  EA[(size_t)d*96 + j] = s;
  if (j < 32) EA[(size_t)d*96 + 64 + j] = (j==0) ? (float)(e-b) : 0.f;
}

// ---------------- fp32 -> bf16 convert ----------------
__global__ void k_f2b(const float* __restrict__ S, short* __restrict__ D, int n4){
  int i = blockIdx.x*256 + threadIdx.x;
  if (i >= n4) return;
  float4 v = ((const float4*)S)[i];
  short4x o;
  o[0]=f2bf(v.x); o[1]=f2bf(v.y); o[2]=f2bf(v.z); o[3]=f2bf(v.w);
  ((short4x*)D)[i] = o;
}

// ---------------- batched weight transposes: z = l*5 + which, fp32[256][256] -> bf16 [n][k] ----
__global__ void k_transW(const float* __restrict__ msg_w1, const float* __restrict__ msg_w2,
                         const float* __restrict__ upd_w1, const float* __restrict__ upd_w2,
                         short* __restrict__ wT){
  int z = blockIdx.z; int l = z/5, w = z%5;
  const float* S;
  switch(w){
    case 0: S = msg_w1 + (size_t)l*513*256; break;
    case 1: S = msg_w1 + (size_t)l*513*256 + 256*256; break;
    case 2: S = msg_w2 + (size_t)l*256*256; break;
    case 3: S = upd_w1 + (size_t)l*256*256; break;
    default: S = upd_w2 + (size_t)l*256*256; break;
  }
  short* D = wT + (size_t)z*65536;
  __shared__ float t[32][33];
  int bx = blockIdx.x*32, by = blockIdx.y*32;
  int lx = threadIdx.x & 31, ly = threadIdx.x >> 5;
  #pragma unroll
  for(int r=0;r<4;r++){ int k = ly + r*8; t[k][lx] = S[(size_t)(by+k)*256 + bx+lx]; }
  __syncthreads();
  #pragma unroll
  for(int r=0;r<4;r++){
    int n = ly + r*8;
    D[(size_t)(bx+n)*256 + by+lx] = f2bf(t[lx][n]);
  }
}

// ---------------- uw1_ext [n=256][352] bf16, batched over layers (blockIdx.y=l) ----
// cols 0..255: uw1T[n][m]; cols 256+c: X[n][c] = sum_m ew_aug[c][m]*uw1T[n][m]
__global__ void k_uw1ext(const short* __restrict__ wT, const float* __restrict__ edge_w,
                         const float* __restrict__ edge_b, short* __restrict__ uw1ext4){
  int n = blockIdx.x, l = blockIdx.y, tid = threadIdx.x;
  const short* uw1T = wT + (size_t)(l*5+3)*65536;
  short* dst = uw1ext4 + (size_t)l*256*352 + (size_t)n*352;
  dst[tid] = uw1T[(size_t)n*256 + tid];
  if (tid < 96){
    int c = tid;
    float s = 0.f;
    if (c < 64){
      const float* er = edge_w + (size_t)l*64*256 + (size_t)c*256;
      for(int m=0;m<256;m++) s += bf2f(uw1T[(size_t)n*256+m])*er[m];
    } else if (c == 64){
      const float* er = edge_b + (size_t)l*256;
      for(int m=0;m<256;m++) s += bf2f(uw1T[(size_t)n*256+m])*er[m];
    }
    dst[256 + c] = f2bf(s);
  }
}

// ---------------- biasm accumulation, batched over layers (blockIdx.y=l) ----------------
__global__ void k_biasm_acc(const float* __restrict__ node_b, const float* __restrict__ msg_w1,
                            const float* __restrict__ msg_b1, float* __restrict__ biasm4){
  int j = threadIdx.x;
  int b = blockIdx.x, l = blockIdx.y;
  const float* nb  = node_b + l*256;
  const float* w1  = msg_w1 + (size_t)l*513*256;
  float* biasm = biasm4 + l*256;
  if (b == 16){ atomicAdd(&biasm[j], msg_b1[l*256+j]); return; }
  float s = 0.f;
  for(int k = b*16; k < b*16+16; k++)
    s += nb[k]*(w1[(size_t)k*256+j] + w1[(size_t)(256+k)*256+j]);
  atomicAdd(&biasm[j], s);
}

// ---------------- biasm += ub2_{l-1} @ (Wa_l + Wb_l), l = blockIdx.x+1 ----------------
__global__ void k_biasfold(const float* __restrict__ upd_b2, const short* __restrict__ WabT4,
                           float* __restrict__ biasm4){
  int l = blockIdx.x + 1;           // 1..3
  int j = threadIdx.x;
  const float* ub2 = upd_b2 + (size_t)(l-1)*256;
  const short* W = WabT4 + (size_t)l*131072;
  float s = 0.f;
  for(int k=0;k<256;k++)
    s += ub2[k]*(bf2f(W[(size_t)j*256+k]) + bf2f(W[(size_t)(256+j)*256+k]));
  biasm4[l*256 + j] += s;
}

// ---------------- bf16 MFMA GEMM: C[M,Nld] = A[M,K] @ BT[N,K]^T (+bias)(+silu) ------
// AF32: A fp32 (converted during staging). AEXT: dual-source A = [A fp32 stride 256 | A2 fp32 stride 96].
// blockIdx.z applies element strides AzStr/BzStr/CzStr (batched small GEMMs).
template<int K_REAL, int K_LDS, int AF32, int AEXT, int BIAS, int ACT, int OF32, int OBF16>
__global__ __launch_bounds__(256)
void k_gemm_mfma(const void* __restrict__ A, const float* __restrict__ A2,
                 const short* __restrict__ BT,
                 const float* __restrict__ bias, float* __restrict__ Cf,
                 short* __restrict__ Cb, int M, int Nld,
                 int AzStr, int BzStr, int CzStr){
  __shared__ __align__(16) short As[32][K_LDS];
  const int CHL = K_LDS/8, CH = K_REAL/8;
  int tid = threadIdx.x;
  int zz = blockIdx.z;
  const short* Ab = (const short*)A + (size_t)zz*AzStr;
  const float* Af = (const float*)A + (size_t)zz*AzStr;
  BT += (size_t)zz*BzStr;
  int m0 = blockIdx.y*32, n0 = blockIdx.x*256;
  for(int c = tid; c < 32*CHL; c += 256){
    int row = c / CHL, ch = c % CHL;
    short8 v = (short8){0,0,0,0,0,0,0,0};
    if (AEXT){
      if (ch < 32){
        float4 f0 = *(const float4*)&Af[(size_t)(m0+row)*256 + ch*8];
        float4 f1 = *(const float4*)&Af[(size_t)(m0+row)*256 + ch*8 + 4];
        v[0]=f2bf(f0.x); v[1]=f2bf(f0.y); v[2]=f2bf(f0.z); v[3]=f2bf(f0.w);
        v[4]=f2bf(f1.x); v[5]=f2bf(f1.y); v[6]=f2bf(f1.z); v[7]=f2bf(f1.w);
      } else if (ch < 44){
        float4 f0 = *(const float4*)&A2[(size_t)(m0+row)*96 + (ch-32)*8];
        float4 f1 = *(const float4*)&A2[(size_t)(m0+row)*96 + (ch-32)*8 + 4];
        v[0]=f2bf(f0.x); v[1]=f2bf(f0.y); v[2]=f2bf(f0.z); v[3]=f2bf(f0.w);
        v[4]=f2bf(f1.x); v[5]=f2bf(f1.y); v[6]=f2bf(f1.z); v[7]=f2bf(f1.w);
      }
    } else if (ch < CH) {
      if (AF32){
        float4 f0 = *(const float4*)&Af[(size_t)(m0+row)*K_REAL + ch*8];
        float4 f1 = *(const float4*)&Af[(size_t)(m0+row)*K_REAL + ch*8 + 4];
        v[0]=f2bf(f0.x); v[1]=f2bf(f0.y); v[2]=f2bf(f0.z); v[3]=f2bf(f0.w);
        v[4]=f2bf(f1.x); v[5]=f2bf(f1.y); v[6]=f2bf(f1.z); v[7]=f2bf(f1.w);
      } else {
        v = *(const short8*)&Ab[(size_t)(m0+row)*K_REAL + ch*8];
      }
    }
    *(short8*)&As[row][(ch ^ (row&7))*8] = v;
  }
  __syncthreads();
  int wid = tid>>6, lane = tid&63, l15 = lane&15, lq = lane>>4;
  int ncol0 = n0 + wid*64;
  f32x4 acc[2][4];
  #pragma unroll
  for(int mt=0;mt<2;mt++)
    #pragma unroll
    for(int nt=0;nt<4;nt++) acc[mt][nt] = (f32x4){0.f,0.f,0.f,0.f};
  for(int k0=0;k0<K_REAL;k0+=32){
    int kc = k0 + 8*lq;
    short8 a[2], b[4];
    #pragma unroll
    for(int mt=0;mt<2;mt++){
      int row = mt*16 + l15;
      a[mt] = *(const short8*)&As[row][kc ^ ((row&7)<<3)];
    }
    #pragma unroll
    for(int nt=0;nt<4;nt++){
      int col = ncol0 + nt*16 + l15;
      b[nt] = *(const short8*)&BT[(size_t)col*K_REAL + kc];
    }
    #pragma unroll
    for(int mt=0;mt<2;mt++)
      #pragma unroll
      for(int nt=0;nt<4;nt++)
        acc[mt][nt] = __builtin_amdgcn_mfma_f32_16x16x32_bf16(a[mt], b[nt], acc[mt][nt], 0, 0, 0);
  }
  #pragma unroll
  for(int mt=0;mt<2;mt++){
    #pragma unroll
    for(int nt=0;nt<4;nt++){
      int col = ncol0 + nt*16 + l15;
      float bb = BIAS ? bias[col] : 0.f;
      #pragma unroll
      for(int r=0;r<4;r++){
        int row = m0 + mt*16 + lq*4 + r;
        float v = acc[mt][nt][r] + bb;
        if (ACT) v = silu_f(v);
        if (OF32)  Cf[(size_t)zz*CzStr + (size_t)row*Nld + col] = v;
        if (OBF16) Cb[(size_t)zz*CzStr + (size_t)row*Nld + col] = f2bf(v);
      }
    }
  }
}

// ---------------- fused edge kernel (MFMA + bf16 single-pass segmented reduce) ----------------
// Edges sorted by dst. 32 edges/block. r5 gather (unconditional strided). out staged bf16
// [256][34] (17KB union -> 9 blocks/CU). Per-column run scan, one atomicAdd per distinct dst.
__global__ __launch_bounds__(256)
void k_edge_mfma(const short* __restrict__ t_ab,
                 const float* __restrict__ dist_s,
                 const int* __restrict__ src_s, const int* __restrict__ dst_s,
                 const float* __restrict__ w1c, const float* __restrict__ biasm,
                 const short* __restrict__ w2T, const float* __restrict__ b2,
                 float* __restrict__ aggr)
{
  // union: h [32][256] bf16 (16KB) | outl [256][34] bf16 (17KB)
  __shared__ __align__(16) unsigned char ulds[256*34*2];
  short (*h)[256] = (short(*)[256])ulds;
  short* outl = (short*)ulds;
  __shared__ int sdst[32], ssrc[32];
  __shared__ float sdist[32];
  int tid = threadIdx.x;
  int e0 = blockIdx.x*32;
  if (tid < 32){
    sdst[tid] = dst_s[e0 + tid];
    ssrc[tid] = src_s[e0 + tid];
    sdist[tid] = dist_s[e0 + tid];
  }
  __syncthreads();
  int wid = tid>>6, lane = tid&63;
  int half = lane>>5, cl = lane&31;          // 16B chunk: cols 8cl..8cl+7
  float wc8[8], bm8[8];
  {
    float4 w0 = *(const float4*)&w1c[8*cl], w1v = *(const float4*)&w1c[8*cl+4];
    float4 b0 = *(const float4*)&biasm[8*cl], b1v = *(const float4*)&biasm[8*cl+4];
    wc8[0]=w0.x; wc8[1]=w0.y; wc8[2]=w0.z; wc8[3]=w0.w;
    wc8[4]=w1v.x; wc8[5]=w1v.y; wc8[6]=w1v.z; wc8[7]=w1v.w;
    bm8[0]=b0.x; bm8[1]=b0.y; bm8[2]=b0.z; bm8[3]=b0.w;
    bm8[4]=b1v.x; bm8[5]=b1v.y; bm8[6]=b1v.z; bm8[7]=b1v.w;
  }
  #pragma unroll
  for(int p=0;p<4;p++){
    int e = wid*8 + p*2 + half;
    int d = sdst[e], s = ssrc[e];
    float de = sdist[e];
    short8 va = *(const short8*)&t_ab[(size_t)d*512 + 8*cl];
    short8 vb = *(const short8*)&t_ab[(size_t)s*512 + 256 + 8*cl];
    short8 hv;
    #pragma unroll
    for(int i=0;i<8;i++){
      float f = bf2f(va[i]) + bf2f(vb[i]) + de*wc8[i] + bm8[i];
      hv[i] = f2bf(silu_f(f));
    }
    *(short8*)&h[e][(8*cl) ^ ((e&7)<<3)] = hv;
  }
  __syncthreads();

  int l15 = lane & 15, lq = lane >> 4;
  int nb = wid*64;
  f32x4 acc[2][4];
  #pragma unroll
  for(int mt=0;mt<2;mt++)
    #pragma unroll
    for(int nt=0;nt<4;nt++) acc[mt][nt] = (f32x4){0.f,0.f,0.f,0.f};

  for(int k0=0;k0<256;k0+=32){
    int kc = k0 + 8*lq;
    short8 a[2], b[4];
    #pragma unroll
    for(int mt=0;mt<2;mt++){
      int row = mt*16 + l15;
      a[mt] = *(const short8*)&h[row][kc ^ ((row&7)<<3)];
    }
    #pragma unroll
    for(int nt=0;nt<4;nt++){
      int col = nb + nt*16 + l15;
      b[nt] = *(const short8*)&w2T[(size_t)col*256 + kc];
    }
    #pragma unroll
    for(int mt=0;mt<2;mt++)
      #pragma unroll
      for(int nt=0;nt<4;nt++)
        acc[mt][nt] = __builtin_amdgcn_mfma_f32_16x16x32_bf16(a[mt], b[nt], acc[mt][nt], 0, 0, 0);
  }
  __syncthreads();   // all h reads complete before outl overwrites the union

  // single-pass epilogue (bf16 staging) + segmented scan over 32 edges
  #pragma unroll
  for(int mt=0;mt<2;mt++){
    #pragma unroll
    for(int nt=0;nt<4;nt++){
      int col = nb + nt*16 + l15;
      float bb = b2[col];
      #pragma unroll
      for(int r=0;r<4;r++){
        int row = mt*16 + lq*4 + r;
        outl[col*34 + row] = f2bf(silu_f(acc[mt][nt][r] + bb));
      }
    }
  }
  __syncthreads();

  int j = tid;
  float accu = 0.f;
  int prev = sdst[0];
  #pragma unroll
  for(int e=0;e<32;e++){
    int d = sdst[e];
    if (d != prev){
      atomicAdd(&aggr[(size_t)prev*256 + j], accu);
      accu = 0.f; prev = d;
    }
    accu += bf2f(outl[j*34 + e]);
  }
  atomicAdd(&aggr[(size_t)prev*256 + j], accu);
}

// ---------------- batch-segmented pooling ----------------
__global__ void k_ghist(const int* __restrict__ batch, int* __restrict__ gcnt){
  int n = blockIdx.x*256 + threadIdx.x;
  if (n >= N_NODES) return;
  atomicAdd(&gcnt[batch[n]], 1);
}
__global__ void k_gscan(const int* __restrict__ gcnt, int* __restrict__ gptr){
  if (threadIdx.x == 0){
    int s = 0;
    for(int g=0; g<NGRAPH; g++){ gptr[g]=s; s += gcnt[g]; }
    gptr[NGRAPH] = s;
  }
}
__global__ void k_pool_seg(const float* __restrict__ x, const int* __restrict__ gptr,
                           float* __restrict__ pooled){
  int g = blockIdx.x, j = threadIdx.x;
  int b = gptr[g], e = gptr[g+1];
  float s = 0.f;
  for(int n=b; n<e; n++) s += x[(size_t)n*256 + j];
  pooled[g*256 + j] = s;
}

// ---------------- head ----------------
__global__ void k_head(const float* __restrict__ pooled, const float* __restrict__ fw1,
                       const float* __restrict__ fb1, const float* __restrict__ fw2,
                       const float* __restrict__ fb2, float* __restrict__ out){
  __shared__ float red[256];
  int g = blockIdx.x, j = threadIdx.x;
  float s = fb1[j];
  const float* p = &pooled[g*256];
  for(int k=0;k<256;k++) s += p[k]*fw1[k*256+j];
  float hv = silu_f(s)*fw2[j];
  red[j]=hv; __syncthreads();
  for(int off=128;off>0;off>>=1){ if(j<off) red[j]+=red[j+off]; __syncthreads(); }
  if(j==0) out[g] = red[0] + fb2[0];
}

extern "C" void kernel_launch(void* const* d_in, const int* in_sizes, int n_in,
                              void* d_out, int out_size, void* d_ws, size_t ws_size,
                              hipStream_t stream) {
  const float* x_in      = (const float*)d_in[0];
  const float* edge_attr = (const float*)d_in[1];
  const float* pos       = (const float*)d_in[2];
  const int*   ei        = (const int*)d_in[3];
  const int*   batch     = (const int*)d_in[4];
  const float* node_w    = (const float*)d_in[5];
  const float* node_b    = (const float*)d_in[6];
  const float* edge_w    = (const float*)d_in[7];
  const float* edge_b    = (const float*)d_in[8];
  const float* msg_w1    = (const float*)d_in[9];
  const float* msg_b1    = (const float*)d_in[10];
  const float* msg_w2    = (const float*)d_in[11];
  const float* msg_b2    = (const float*)d_in[12];
  const float* upd_w1    = (const float*)d_in[13];
  const float* upd_b1    = (const float*)d_in[14];
  const float* upd_w2    = (const float*)d_in[15];
  const float* upd_b2    = (const float*)d_in[16];
  const float* fc_w1     = (const float*)d_in[17];
  const float* fc_b1     = (const float*)d_in[18];
  const float* fc_w2     = (const float*)d_in[19];
  const float* fc_b2     = (const float*)d_in[20];
  float* out = (float*)d_out;

  float* ws = (float*)d_ws;
  // CSR / sort
  int* cnt     = (int*)ws; ws += N_NODES;
  int* off     = (int*)ws; ws += N_NODES;
  int* row_ptr = (int*)ws; ws += N_NODES+4;
  int* src_s   = (int*)ws; ws += N_EDGES;
  int* dst_s   = (int*)ws; ws += N_EDGES;
  int* eid_s   = (int*)ws; ws += N_EDGES;
  float* dist_s= ws; ws += N_EDGES;
  int* gcnt    = (int*)ws; ws += NGRAPH;
  int* gptr    = (int*)ws; ws += NGRAPH+4;
  // weights (all layers, prepped once per call)
  short* wT      = (short*)ws; ws += 20*65536/2;     // [l*5+which][256][256] bf16
  short* nw_bf4  = (short*)ws; ws += 4*65536/2;      // node_w bf16
  short* uw2_bf4 = (short*)ws; ws += 4*65536/2;      // upd_w2 bf16 (row-major, for fold)
  short* uw1ext4 = (short*)ws; ws += 4*256*352/2 + 64;  // [l][256][352] bf16
  short* WabT4   = (short*)ws; ws += 4*131072/2;     // [l][512][256] bf16
  short* WfoldT4 = (short*)ws; ws += 3*131072/2;     // [l=1..3][512][256] bf16
  float* biasm4  = ws; ws += 4*256;
  // data
  short* h_bf   = (short*)ws; ws += (size_t)N_NODES*256/2;   // silu(upd1) bf16
  float* EA_aug = ws; ws += (size_t)N_NODES*96;
  float* tabreg = ws; ws += (size_t)N_NODES*256;             // t_ab bf16 [N][512]
  float* aggr   = ws; ws += (size_t)N_NODES*256;
  float* pooled = ws; ws += NGRAPH*256;

  short* t_ab   = (short*)tabreg;
  float* xfinal = aggr;                              // alias: aggr dead after upd1

  // ---- one-time: CSR sort, distances, EA aggregation, batch ptrs, weight prep ----
  hipMemsetAsync(cnt, 0, N_NODES*sizeof(int), stream);
  k_hist<<<(N_EDGES+255)/256, 256, 0, stream>>>(ei, cnt);
  k_scan<<<1, 256, 0, stream>>>(cnt, row_ptr, off);
  k_scatter<<<(N_EDGES+255)/256, 256, 0, stream>>>(ei, off, src_s, dst_s, eid_s);
  k_dist_s<<<(N_EDGES+255)/256, 256, 0, stream>>>(src_s, dst_s, pos, dist_s);
  k_eaagg_s<<<N_NODES/4, 256, 0, stream>>>(row_ptr, eid_s, edge_attr, EA_aug);
  hipMemsetAsync(gcnt, 0, NGRAPH*sizeof(int), stream);
  k_ghist<<<(N_NODES+255)/256, 256, 0, stream>>>(batch, gcnt);
  k_gscan<<<1, 64, 0, stream>>>(gcnt, gptr);

  k_transW<<<dim3(8,8,20), 256, 0, stream>>>(msg_w1, msg_w2, upd_w1, upd_w2, wT);
  k_f2b<<<256, 256, 0, stream>>>(node_w, nw_bf4, 4*65536/4);
  k_f2b<<<256, 256, 0, stream>>>(upd_w2, uw2_bf4, 4*65536/4);
  k_uw1ext<<<dim3(256,4), 256, 0, stream>>>(wT, edge_w, edge_b, uw1ext4);
  hipMemsetAsync(biasm4, 0, 4*256*sizeof(float), stream);
  k_biasm_acc<<<dim3(17,4), 256, 0, stream>>>(node_b, msg_w1, msg_b1, biasm4);
  // fold node_w through msg_w1 halves, batched over layers (z = l):
  k_gemm_mfma<256,256,0,0,0,0,0,1><<<dim3(1,8,4), 256, 0, stream>>>(
      wT,         nullptr, nw_bf4, nullptr, nullptr, WabT4,         256, 256, 5*65536, 65536, 131072);
  k_gemm_mfma<256,256,0,0,0,0,0,1><<<dim3(1,8,4), 256, 0, stream>>>(
      wT + 65536, nullptr, nw_bf4, nullptr, nullptr, WabT4 + 65536, 256, 256, 5*65536, 65536, 131072);
  // fold upd_w2 into next layer's Wab: WfoldT[l] = WabT4[l] @ uw2_{l-1}, l=1..3 (z=0..2)
  k_gemm_mfma<256,256,0,0,0,0,0,1><<<dim3(1,16,3), 256, 0, stream>>>(
      WabT4 + 131072, nullptr, uw2_bf4, nullptr, nullptr, WfoldT4, 512, 256, 131072, 65536, 131072);
  // biasm_l += ub2_{l-1} @ (Wa_l + Wb_l), l=1..3
  k_biasfold<<<3, 256, 0, stream>>>(upd_b2, WabT4, biasm4);

  // t_ab for layer 0: x_in @ [Wa0|Wb0] (fp32 A staged)
  k_gemm_mfma<256,256,1,0,0,0,0,1><<<dim3(2,625), 256, 0, stream>>>(
      x_in, nullptr, WabT4, nullptr, nullptr, t_ab, N_NODES, 512, 0,0,0);

  for(int l=0;l<4;l++){
    const float* w1  = msg_w1 + (size_t)l*513*256;
    const float* mb2 = msg_b2 + l*256;
    const float* ub1 = upd_b1 + l*256;
    const float* ub2 = upd_b2 + l*256;
    const short* w2T_l  = wT + (size_t)(l*5+2)*65536;
    const short* uw2T_l = wT + (size_t)(l*5+4)*65536;

    // zero aggr; edge kernel accumulates message sums (EA path folded into upd1)
    hipMemsetAsync(aggr, 0, (size_t)N_NODES*256*sizeof(float), stream);

    k_edge_mfma<<<N_EDGES/32, 256, 0, stream>>>(t_ab, dist_s, src_s, dst_s,
                                                w1 + 512*256, biasm4 + l*256,
                                                w2T_l, mb2, aggr);

    // h_bf = silu([aggr | EA_aug] @ uw1_ext + ub1)   (K=352 dual-source A)
    k_gemm_mfma<352,384,1,1,1,1,0,1><<<dim3(1,625), 256, 0, stream>>>(
        aggr, EA_aug, uw1ext4 + (size_t)l*256*352, ub1, nullptr, h_bf, N_NODES, 256, 0,0,0);

    if (l < 3)
      // next-layer t_ab directly: h_bf @ WfoldT[l+1]  (upd2 folded; bias in biasm4[l+1])
      k_gemm_mfma<256,256,0,0,0,0,0,1><<<dim3(2,625), 256, 0, stream>>>(
          h_bf, nullptr, WfoldT4 + (size_t)l*131072, nullptr, nullptr, t_ab, N_NODES, 512, 0,0,0);
    else
      // final x for pooling: h_bf @ uw2 + ub2
      k_gemm_mfma<256,256,0,0,1,0,1,0><<<dim3(1,625), 256, 0, stream>>>(
          h_bf, nullptr, uw2T_l, ub2, xfinal, nullptr, N_NODES, 256, 0,0,0);
  }

  k_pool_seg<<<NGRAPH, 256, 0, stream>>>(xfinal, gptr, pooled);
  k_head<<<NGRAPH, 256, 0, stream>>>(pooled, fc_w1, fc_b1, fc_w2, fc_b2, out);
}